// Round 5
// baseline (142.168 us; speedup 1.0000x reference)
//
#include <hip/hip_runtime.h>
#include <hip/hip_bf16.h>

#define B_ 128
#define S_ 513
#define H_ 256
#define SH_ (S_ * H_)

typedef __attribute__((ext_vector_type(8))) short short8;
typedef __attribute__((ext_vector_type(4))) float f32x4;

// Pack 8 fp32 -> 8 bf16 (RNE) via the HW packed converter.
static __device__ inline short8 pack8(float4 a, float4 b) {
    union { short8 s; __hip_bfloat162 h[4]; } u;
    u.h[0] = __float22bfloat162_rn(make_float2(a.x, a.y));
    u.h[1] = __float22bfloat162_rn(make_float2(a.z, a.w));
    u.h[2] = __float22bfloat162_rn(make_float2(b.x, b.y));
    u.h[3] = __float22bfloat162_rn(make_float2(b.z, b.w));
    return u.s;
}

static __device__ inline unsigned short f2bf(float f) {
    union { float f; unsigned int u; } v; v.f = f;
    unsigned int u = v.u;
    unsigned int r = u + 0x7fffu + ((u >> 16) & 1u);
    return (unsigned short)(r >> 16);
}

// Prep: W fp32 -> bf16 (5*256*256 elems) + bias sum (256) into workspace.
__global__ void prep_kernel(const float* __restrict__ W,
                            const float* __restrict__ bias,
                            unsigned short* __restrict__ Wbf,
                            float* __restrict__ bsum) {
    int t = blockIdx.x * 256 + threadIdx.x;
    if (t < 5 * H_ * H_ / 4) {
        float4 v = *(const float4*)(W + (size_t)t * 4);
        ushort4 p;
        p.x = f2bf(v.x); p.y = f2bf(v.y); p.z = f2bf(v.z); p.w = f2bf(v.w);
        *(ushort4*)(Wbf + (size_t)t * 4) = p;
    }
    if (t < H_) {
        float s = 0.f;
#pragma unroll
        for (int i = 0; i < 5; ++i) s += bias[i * H_ + t];
        bsum[t] = s;
    }
}

// One block = one s-position. Block tile: d=256 (m) x batch=128 (n), K=256.
// TRANSPOSED MFMA vs R4: A-operand = W rows (m = d), B-operand = x rows
// (n = batch). C/D layout row=quad*4+reg, col=lane&15 then gives each lane
// 4 CONSECUTIVE d values per acc register -> epilogue is 16 aligned float4
// stores per thread instead of 64 scalar stores (R4's store-issue wall:
// 16.8M scalar stores ~= 27 us of issue).
// 512 threads = 8 waves: wd = w&3 (d-slice), wb = w>>2 (batch half).
// Same R4 winning structure otherwise: all global loads up front, x staged
// to 64 KB swizzled LDS once for full K, ONE barrier, pure LDS+reg MFMA.
template <int MODE>
__global__ __launch_bounds__(512, 2)
void sel_gemm_kernel(const float* __restrict__ x,
                     const void* __restrict__ Wp,
                     const void* __restrict__ bp,
                     float* __restrict__ out) {
    const int s = blockIdx.x;                      // 0..512
    const int m_idx = (s < 3) ? s : ((s & 1) ? 3 : 4);

    // 128 batch-rows x 256 bf16 (64 KB). 16-B chunk c of row r stored at
    // chunk index c ^ (r & 7) -> near-conflict-free staging and frag reads.
    __shared__ unsigned short Xs[128 * 256];

    const int t    = threadIdx.x;
    const int lane = t & 63;
    const int w    = t >> 6;       // 0..7
    const int wd   = w & 3;        // d-slice:     wd*64
    const int wb   = w >> 2;       // batch-slice: wb*64
    const int lrow = lane & 15;
    const int quad = lane >> 4;

    // ---- A fragments: this wave's 64 W-rows (d) x K=256 -> 32 short8/lane.
    short8 afr[4][8];
    if (MODE == 0) {
        const unsigned short* Wb =
            (const unsigned short*)Wp + (size_t)m_idx * H_ * H_;
#pragma unroll
        for (int i = 0; i < 4; ++i) {
            const unsigned short* wrow = Wb + (size_t)(wd * 64 + i * 16 + lrow) * H_;
#pragma unroll
            for (int kk = 0; kk < 8; ++kk)
                afr[i][kk] = *(const short8*)(wrow + kk * 32 + quad * 8);
        }
    } else {
        const float* Wb = (const float*)Wp + (size_t)m_idx * H_ * H_;
#pragma unroll
        for (int i = 0; i < 4; ++i) {
            const float* wrow = Wb + (size_t)(wd * 64 + i * 16 + lrow) * H_;
#pragma unroll
            for (int kk = 0; kk < 8; ++kk) {
                float4 v0 = *(const float4*)(wrow + kk * 32 + quad * 8);
                float4 v1 = *(const float4*)(wrow + kk * 32 + quad * 8 + 4);
                afr[i][kk] = pack8(v0, v1);
            }
        }
    }

    // ---- Stage x: 128 rows x 256 fp32 -> bf16 LDS, swizzled. 8 chunks/thr.
    const float* xs = x + (size_t)s * H_;
#pragma unroll
    for (int i = 0; i < 8; ++i) {
        int flat = i * 512 + t;
        int r = flat >> 5;              // 0..127 (batch)
        int c = flat & 31;              // 16-B chunk (8 bf16) within row
        const float* src = xs + (size_t)r * SH_ + c * 8;
        float4 v0 = *(const float4*)src;
        float4 v1 = *(const float4*)(src + 4);
        *(short8*)&Xs[r * 256 + ((c ^ (r & 7)) * 8)] = pack8(v0, v1);
    }

    f32x4 acc[4][4];                    // [i: d-tile][j: batch-tile]
#pragma unroll
    for (int i = 0; i < 4; ++i)
#pragma unroll
        for (int j = 0; j < 4; ++j) {
            f32x4 z = {0.f, 0.f, 0.f, 0.f};
            acc[i][j] = z;
        }

    __syncthreads();   // the only barrier

    // ---- Pure LDS+register MFMA loop: 8 K-steps of 32.
#pragma unroll
    for (int kk = 0; kk < 8; ++kk) {
        const int cc = kk * 4 + quad;   // 16-B chunk column of lane's frag
        short8 bfr[4];
#pragma unroll
        for (int j = 0; j < 4; ++j) {
            int r = wb * 64 + j * 16 + lrow;
            bfr[j] = *(const short8*)&Xs[r * 256 + ((cc ^ (r & 7)) * 8)];
        }
#pragma unroll
        for (int i = 0; i < 4; ++i)
#pragma unroll
            for (int j = 0; j < 4; ++j)
                acc[i][j] = __builtin_amdgcn_mfma_f32_16x16x32_bf16(
                    afr[i][kk], bfr[j], acc[i][j], 0, 0, 0);
    }

    // ---- Bias along d: lane needs bsum[d0..d0+3] per i, d0 = wd*64+i*16+quad*4.
    f32x4 bsv[4];
    if (MODE == 0) {
        const float* bsum = (const float*)bp;
#pragma unroll
        for (int i = 0; i < 4; ++i)
            bsv[i] = *(const f32x4*)(bsum + wd * 64 + i * 16 + quad * 4);
    } else {
        const float* bias = (const float*)bp;
#pragma unroll
        for (int i = 0; i < 4; ++i) {
            int d0 = wd * 64 + i * 16 + quad * 4;
            f32x4 sum = {0.f, 0.f, 0.f, 0.f};
#pragma unroll
            for (int m5 = 0; m5 < 5; ++m5)
                sum += *(const f32x4*)(bias + m5 * H_ + d0);
            bsv[i] = sum;
        }
    }

    // ---- Epilogue: 16 aligned float4 stores per thread.
    // D layout: m(d) = quad*4 + reg (consecutive in the f32x4!), n(batch)=lrow.
#pragma unroll
    for (int j = 0; j < 4; ++j) {
        const int bg = wb * 64 + j * 16 + lrow;
        float* orow = out + (size_t)bg * SH_ + (size_t)s * H_;
#pragma unroll
        for (int i = 0; i < 4; ++i) {
            const int d0 = wd * 64 + i * 16 + quad * 4;
            f32x4 v = acc[i][j] + bsv[i];
            *(f32x4*)(orow + d0) = v;
        }
    }
}

extern "C" void kernel_launch(void* const* d_in, const int* in_sizes, int n_in,
                              void* d_out, int out_size, void* d_ws, size_t ws_size,
                              hipStream_t stream) {
    const float* x    = (const float*)d_in[0];
    const float* W    = (const float*)d_in[1];
    const float* bias = (const float*)d_in[2];
    float* out = (float*)d_out;

    const size_t w_elems = (size_t)5 * H_ * H_;
    const size_t ws_need = w_elems * sizeof(unsigned short) + H_ * sizeof(float);

    if (ws_size >= ws_need) {
        unsigned short* Wbf = (unsigned short*)d_ws;
        float* bsum = (float*)((char*)d_ws + w_elems * sizeof(unsigned short));
        prep_kernel<<<dim3((w_elems / 4 + 255) / 256), dim3(256), 0, stream>>>(
            W, bias, Wbf, bsum);
        sel_gemm_kernel<0><<<dim3(S_), dim3(512), 0, stream>>>(
            x, (const void*)Wbf, (const void*)bsum, out);
    } else {
        sel_gemm_kernel<1><<<dim3(S_), dim3(512), 0, stream>>>(
            x, (const void*)W, (const void*)bias, out);
    }
}